// Round 1
// 446.539 us; speedup vs baseline: 1.5632x; 1.5632x over previous
//
#include <hip/hip_runtime.h>

// LSTM cell: fp32 inputs, fp32 output (bf16-lenient compare).
// gates[B,3H] = x@Wx^T + h@Wh^T + b; new_c = sig(gf)*c + sig(gi)*tanh(gg).
// M=16384, N=1024 x 3 gates, K=2048 (x||h fused).
//
// v2: 3-dispatch pipeline.
//  1) pack_a: x||h -> bf16 workspace, tiled [mt][kt][128x64 swizzled LDS image]
//  2) pack_w: 6 weights -> bf16 workspace, tiled [nt][kt][3][64x64 swizzled image]
//  3) lstm_gemm: m97-structure GEMM: global_load_lds(16B) staging direct to LDS,
//     double-buffered, BK=64, XOR-swizzled ds_read_b128 (conflict-free),
//     MFMA 32x32x16 bf16, fused sigmoid/tanh epilogue, XCD-bijective swizzle.
// Swizzle: element k of row r lives at byte (2k)^((r&7)<<4) within the 128B row
// (involution; applied at pack time on the SOURCE, linear global_load_lds dest,
//  re-applied on the ds_read address — rule "both-sides-or-neither").

#define HS      1024
#define K_TOTAL 2048
#define NKT     32            // 2048 / 64
#define A_TILE  16384         // 128 rows x 64 k x 2B
#define W_TILE  24576         // 3 gates x 64 rows x 64 k x 2B
#define BUFB    40960         // A_TILE + W_TILE per LDS buffer

typedef __bf16 bf16;
typedef bf16  bf16x4  __attribute__((ext_vector_type(4)));
typedef bf16  bf16x8  __attribute__((ext_vector_type(8)));
typedef float f32x4   __attribute__((ext_vector_type(4)));
typedef float f32x16  __attribute__((ext_vector_type(16)));

// ---------------------------------------------------------------------------
// async 16B global -> LDS (wave-uniform LDS base + lane*16)
__device__ __forceinline__ void cp16(void* lds, const void* g) {
  __builtin_amdgcn_global_load_lds(
      (const __attribute__((address_space(1))) void*)g,
      (__attribute__((address_space(3))) void*)lds, 16, 0, 0);
}

__device__ __forceinline__ bf16x8 cvt8(const f32x4 v0, const f32x4 v1) {
  bf16x8 o;
  o[0] = (bf16)v0[0]; o[1] = (bf16)v0[1]; o[2] = (bf16)v0[2]; o[3] = (bf16)v0[3];
  o[4] = (bf16)v1[0]; o[5] = (bf16)v1[1]; o[6] = (bf16)v1[2]; o[7] = (bf16)v1[3];
  return o;
}

// ---------------------------------------------------------------------------
// pack_a: A = [x | h] -> bf16, layout [mt(128 rows)][kt(64 k)][16KB image].
// Image byte o: row = o>>7, k-byte = (o&127) ^ ((row&7)<<4).
__global__ __launch_bounds__(256) void pack_a(const float* __restrict__ x,
                                              const float* __restrict__ h,
                                              bf16* __restrict__ Aws) {
  const unsigned gt   = blockIdx.x * 256 + threadIdx.x;
  const unsigned Lb   = gt * 16;
  const unsigned tile = Lb >> 14;
  const unsigned o    = Lb & 16383u;
  const unsigned row  = o >> 7;
  const unsigned kb   = (o & 127u) ^ ((row & 7u) << 4);
  const unsigned mt   = tile >> 5;
  const unsigned kt   = tile & 31u;
  const unsigned m    = mt * 128 + row;
  const unsigned kg   = kt * 64 + (kb >> 1);
  const float* src = (kg < 1024u) ? (x + (size_t)m * HS + kg)
                                  : (h + (size_t)m * HS + (kg - 1024u));
  const f32x4 v0 = *(const f32x4*)src;
  const f32x4 v1 = *(const f32x4*)(src + 4);
  *(bf16x8*)((char*)Aws + Lb) = cvt8(v0, v1);
}

// pack_w: W -> bf16, layout [nt(64 n)][kt(64 k)][gate(3)][8KB image].
__global__ __launch_bounds__(256) void pack_w(
    const float* __restrict__ w_ii, const float* __restrict__ w_hi,
    const float* __restrict__ w_if, const float* __restrict__ w_hf,
    const float* __restrict__ w_ig, const float* __restrict__ w_hg,
    bf16* __restrict__ Wws) {
  const unsigned gt  = blockIdx.x * 256 + threadIdx.x;
  const unsigned Lb  = gt * 16;
  const unsigned nt  = Lb / 786432u;          // 32 kt * 24576
  const unsigned r1  = Lb % 786432u;
  const unsigned kt  = r1 / 24576u;
  const unsigned r2  = r1 % 24576u;
  const unsigned g   = r2 >> 13;
  const unsigned o   = r2 & 8191u;
  const unsigned row = o >> 7;
  const unsigned kb  = (o & 127u) ^ ((row & 7u) << 4);
  const unsigned n   = nt * 64 + row;
  const unsigned kg  = kt * 64 + (kb >> 1);
  const float* wx = (g == 0) ? w_ii : (g == 1) ? w_if : w_ig;
  const float* wh = (g == 0) ? w_hi : (g == 1) ? w_hf : w_hg;
  const float* src = (kg < 1024u) ? (wx + (size_t)n * HS + kg)
                                  : (wh + (size_t)n * HS + (kg - 1024u));
  const f32x4 v0 = *(const f32x4*)src;
  const f32x4 v1 = *(const f32x4*)(src + 4);
  *(bf16x8*)((char*)Wws + Lb) = cvt8(v0, v1);
}

// ---------------------------------------------------------------------------
// GEMM: block = 128M x 64N x 3 gates, 256 thr = 4 waves (2x2),
// wave = 64M x 32N x 3. BK=64 -> 32 iters. LDS 2 x 40KB -> 2 blocks/CU.
__global__ __launch_bounds__(256, 2) void lstm_gemm(
    const bf16* __restrict__ Aws, const bf16* __restrict__ Wws,
    const float* __restrict__ c,
    const float* __restrict__ b_ii, const float* __restrict__ b_hi,
    const float* __restrict__ b_if, const float* __restrict__ b_hf,
    const float* __restrict__ b_ig, const float* __restrict__ b_hg,
    float* __restrict__ out)
{
  __shared__ __align__(16) char smem[2 * BUFB];   // 80 KB

  const int tid  = threadIdx.x;
  const int lane = tid & 63;
  const int wave = tid >> 6;

  // XCD-bijective swizzle: 2048 wgs, 8 XCDs, 256 contiguous wgs per XCD.
  // Each XCD covers 16 mt-panels x all 16 nt: A stays in its 4MB L2.
  const int bid = blockIdx.x;
  const int wg  = (bid & 7) * 256 + (bid >> 3);
  const int nt  = wg & 15;     // nt-minor: consecutive wgs share A-panel
  const int mt  = wg >> 4;
  const int m0  = mt * 128;
  const int n0  = nt * 64;
  const int wm  = (wave & 1) * 64;
  const int wn  = (wave >> 1) * 32;

  const char* Apan = (const char*)Aws + (size_t)mt * (NKT * A_TILE);
  const char* Wpan = (const char*)Wws + (size_t)nt * (NKT * W_TILE);

  const int aoff = wave * 4 * 1024;   // 4 A-chunks per wave
  const int boff = wave * 6 * 1024;   // 6 W-chunks per wave
  const int lb   = lane * 16;

  f32x16 acc[3][2] = {};

  // stage K-tile t into LDS buffer sel (40 global_load_lds / block)
  auto stage = [&](int t, int sel) {
    char* bufA = smem + sel * BUFB;
    char* bufB = bufA + A_TILE;
    const char* At = Apan + t * A_TILE + aoff + lb;
    const char* Wt = Wpan + (size_t)t * W_TILE + boff + lb;
#pragma unroll
    for (int i = 0; i < 4; ++i) cp16(bufA + aoff + i * 1024, At + i * 1024);
#pragma unroll
    for (int i = 0; i < 6; ++i) cp16(bufB + boff + i * 1024, Wt + i * 1024);
  };

  stage(0, 0);
  __syncthreads();

  const int fr    = lane & 31;
  const int fk8b  = (lane >> 5) * 16;   // byte offset of 8-elem half
  const int xr    = (fr & 7) << 4;      // swizzle term (row&7 == fr&7 here)

  for (int t = 0; t < NKT; ++t) {
    if (t < NKT - 1) stage(t + 1, (t + 1) & 1);

    const char* bufA  = smem + (t & 1) * BUFB;
    const char* bufB  = bufA + A_TILE;
    const char* arow0 = bufA + (wm + fr) * 128;
    const char* arow1 = bufA + (wm + 32 + fr) * 128;
    const char* brow  = bufB + (wn + fr) * 128;

#pragma unroll
    for (int ks = 0; ks < 4; ++ks) {
      const int kb = (ks * 32 + fk8b) ^ xr;
      const bf16x8 a0 = *(const bf16x8*)(arow0 + kb);
      const bf16x8 a1 = *(const bf16x8*)(arow1 + kb);
#pragma unroll
      for (int g = 0; g < 3; ++g) {
        const bf16x8 b = *(const bf16x8*)(brow + g * 8192 + kb);
        acc[g][0] = __builtin_amdgcn_mfma_f32_32x32x16_bf16(a0, b, acc[g][0], 0, 0, 0);
        acc[g][1] = __builtin_amdgcn_mfma_f32_32x32x16_bf16(a1, b, acc[g][1], 0, 0, 0);
      }
    }
    __syncthreads();
  }

  // Epilogue. C/D layout (32x32): col n = lane&31, row = (r&3)+8*(r>>2)+4*(lane>>5).
  const int n   = n0 + wn + (lane & 31);
  const int rb  = (lane >> 5) * 4;
  const float bi  = b_ii[n] + b_hi[n];
  const float bf_ = b_if[n] + b_hf[n];
  const float bg  = b_ig[n] + b_hg[n];
#pragma unroll
  for (int i = 0; i < 2; ++i) {
#pragma unroll
    for (int r = 0; r < 16; ++r) {
      const int m = m0 + wm + i * 32 + (r & 3) + 8 * (r >> 2) + rb;
      const size_t idx = (size_t)m * HS + n;
      const float gi = acc[0][i][r] + bi;
      const float gf = acc[1][i][r] + bf_;
      const float gg = acc[2][i][r] + bg;
      const float it = 1.f / (1.f + __expf(-gi));
      const float ft = 1.f / (1.f + __expf(-gf));
      const float e2 = __expf(-2.f * gg);
      const float gt = (1.f - e2) / (1.f + e2);  // tanh
      out[idx] = ft * c[idx] + it * gt;
    }
  }
}

// ===========================================================================
// Legacy fallback (previous verified kernel) — used only if workspace too small.
#define BK      32
#define NITER   (K_TOTAL / BK)

__device__ __forceinline__ void ldpanel(const float* __restrict__ src, int tid,
                                        f32x4* __restrict__ v) {
#pragma unroll
  for (int b = 0; b < 2; ++b) {
    const int cc  = tid + b * 256;
    const int row = cc >> 3;
    const int col = (cc & 7) * 4;
    v[b] = *(const f32x4*)(src + (size_t)row * HS + col);
  }
}

__device__ __forceinline__ void stpanel(bf16* __restrict__ dst, int tid,
                                        const f32x4* __restrict__ v) {
#pragma unroll
  for (int b = 0; b < 2; ++b) {
    const int cc  = tid + b * 256;
    const int row = cc >> 3;
    const int col = (cc & 7) * 4;
    bf16x4 o;
    o[0] = (bf16)v[b][0]; o[1] = (bf16)v[b][1];
    o[2] = (bf16)v[b][2]; o[3] = (bf16)v[b][3];
    *(bf16x4*)(dst + row * 32 + col) = o;
  }
}

__device__ __forceinline__ void get_srcs(
    int k, int m0, int n0,
    const float* __restrict__ x, const float* __restrict__ h,
    const float* __restrict__ w_ii, const float* __restrict__ w_hi,
    const float* __restrict__ w_if, const float* __restrict__ w_hf,
    const float* __restrict__ w_ig, const float* __restrict__ w_hg,
    const float* s[5]) {
  const int kk = k * BK;
  const float* Ag; const float* w0; const float* w1; const float* w2; int kl;
  if (kk < 1024) { Ag = x; w0 = w_ii; w1 = w_if; w2 = w_ig; kl = kk; }
  else           { Ag = h; w0 = w_hi; w1 = w_hf; w2 = w_hg; kl = kk - 1024; }
  s[0] = Ag + (size_t)m0 * HS + kl;
  s[1] = Ag + (size_t)(m0 + 64) * HS + kl;
  s[2] = w0 + (size_t)n0 * HS + kl;
  s[3] = w1 + (size_t)n0 * HS + kl;
  s[4] = w2 + (size_t)n0 * HS + kl;
}

__global__ __launch_bounds__(256, 2) void lstm_fused(
    const float* __restrict__ x, const float* __restrict__ h,
    const float* __restrict__ c,
    const float* __restrict__ w_ii, const float* __restrict__ w_hi,
    const float* __restrict__ w_if, const float* __restrict__ w_hf,
    const float* __restrict__ w_ig, const float* __restrict__ w_hg,
    const float* __restrict__ b_ii, const float* __restrict__ b_hi,
    const float* __restrict__ b_if, const float* __restrict__ b_hf,
    const float* __restrict__ b_ig, const float* __restrict__ b_hg,
    float* __restrict__ out)
{
  __shared__ bf16 smem[2 * 10240];

  const int tid  = threadIdx.x;
  const int lane = tid & 63;
  const int wave = tid >> 6;

  const int bid = blockIdx.x;
  const int nt  = bid & 15;
  const int mt  = bid >> 4;
  const int m0  = mt * 128;
  const int n0  = nt * 64;
  const int wm  = (wave & 1) * 64;
  const int wn  = (wave >> 1) * 32;

  f32x16 acc[3][2] = {};

  {
    const float* s[5];
    get_srcs(0, m0, n0, x, h, w_ii, w_hi, w_if, w_hf, w_ig, w_hg, s);
    f32x4 pf[5][2];
#pragma unroll
    for (int p = 0; p < 5; ++p) ldpanel(s[p], tid, pf[p]);
    bf16* A0 = smem;
#pragma unroll
    for (int p = 0; p < 5; ++p) stpanel(A0 + p * 2048, tid, pf[p]);
    __syncthreads();
  }

  const int fr  = lane & 31;
  const int fk8 = (lane >> 5) * 8;

  for (int k = 0; k < NITER; ++k) {
    bf16* As = smem + (k & 1) * 10240;
    bf16* Bs = As + 4096;

    f32x4 nf[5][2];
    if (k < NITER - 1) {
      const float* s[5];
      get_srcs(k + 1, m0, n0, x, h, w_ii, w_hi, w_if, w_hf, w_ig, w_hg, s);
#pragma unroll
      for (int p = 0; p < 5; ++p) ldpanel(s[p], tid, nf[p]);
    }

#pragma unroll
    for (int ks = 0; ks < 2; ++ks) {
      const int co = ks * 16 + fk8;
      bf16x8 a0 = *(const bf16x8*)(As + (wm + fr) * 32 + co);
      bf16x8 a1 = *(const bf16x8*)(As + (wm + 32 + fr) * 32 + co);
#pragma unroll
      for (int g = 0; g < 3; ++g) {
        bf16x8 b = *(const bf16x8*)(Bs + g * 2048 + (wn + fr) * 32 + co);
        acc[g][0] = __builtin_amdgcn_mfma_f32_32x32x16_bf16(a0, b, acc[g][0], 0, 0, 0);
        acc[g][1] = __builtin_amdgcn_mfma_f32_32x32x16_bf16(a1, b, acc[g][1], 0, 0, 0);
      }
    }

    if (k < NITER - 1) {
      bf16* An = smem + ((k + 1) & 1) * 10240;
#pragma unroll
      for (int p = 0; p < 5; ++p) stpanel(An + p * 2048, tid, nf[p]);
    }
    __syncthreads();
  }

  const int n   = n0 + wn + (lane & 31);
  const int rb  = (lane >> 5) * 4;
  const float bi  = b_ii[n] + b_hi[n];
  const float bf_ = b_if[n] + b_hf[n];
  const float bg  = b_ig[n] + b_hg[n];
#pragma unroll
  for (int i = 0; i < 2; ++i) {
#pragma unroll
    for (int r = 0; r < 16; ++r) {
      const int m = m0 + wm + i * 32 + (r & 3) + 8 * (r >> 2) + rb;
      const size_t idx = (size_t)m * HS + n;
      const float gi = acc[0][i][r] + bi;
      const float gf = acc[1][i][r] + bf_;
      const float gg = acc[2][i][r] + bg;
      const float it = 1.f / (1.f + __expf(-gi));
      const float ft = 1.f / (1.f + __expf(-gf));
      const float e2 = __expf(-2.f * gg);
      const float gt = (1.f - e2) / (1.f + e2);
      out[idx] = ft * c[idx] + it * gt;
    }
  }
}

// ===========================================================================
extern "C" void kernel_launch(void* const* d_in, const int* in_sizes, int n_in,
                              void* d_out, int out_size, void* d_ws, size_t ws_size,
                              hipStream_t stream) {
  const float* x  = (const float*)d_in[0];
  const float* h  = (const float*)d_in[1];
  const float* c  = (const float*)d_in[2];
  const float* w_ii = (const float*)d_in[3];
  const float* b_ii = (const float*)d_in[4];
  const float* w_hi = (const float*)d_in[5];
  const float* b_hi = (const float*)d_in[6];
  const float* w_if = (const float*)d_in[7];
  const float* b_if = (const float*)d_in[8];
  const float* w_hf = (const float*)d_in[9];
  const float* b_hf = (const float*)d_in[10];
  const float* w_ig = (const float*)d_in[11];
  const float* b_ig = (const float*)d_in[12];
  const float* w_hg = (const float*)d_in[13];
  const float* b_hg = (const float*)d_in[14];
  float* out = (float*)d_out;

  const size_t needA = (size_t)16384 * 2048 * 2;        // 64 MB
  const size_t needW = (size_t)3 * 1024 * 2048 * 2;     // 12 MB

  if (ws_size >= needA + needW) {
    bf16* Aws = (bf16*)d_ws;
    bf16* Wws = (bf16*)((char*)d_ws + needA);
    hipLaunchKernelGGL(pack_a, dim3(16384), dim3(256), 0, stream, x, h, Aws);
    hipLaunchKernelGGL(pack_w, dim3(3072), dim3(256), 0, stream,
                       w_ii, w_hi, w_if, w_hf, w_ig, w_hg, Wws);
    hipLaunchKernelGGL(lstm_gemm, dim3(2048), dim3(256), 0, stream,
                       Aws, Wws, c, b_ii, b_hi, b_if, b_hf, b_ig, b_hg, out);
  } else {
    hipLaunchKernelGGL(lstm_fused, dim3(2048), dim3(256), 0, stream,
                       x, h, c, w_ii, w_hi, w_if, w_hf, w_ig, w_hg,
                       b_ii, b_hi, b_if, b_hf, b_ig, b_hg, out);
  }
}